// Round 2
// baseline (51.624 us; speedup 1.0000x reference)
//
#include <hip/hip_runtime.h>

#define T_LEN 4096
#define H 16
#define N 16
#define D 64

// ---------------------------------------------------------------------------
// Phase 1: per (chunk, head) one wave (64 threads). Lane d owns the full
// n-column of the state (16 regs). Computes the chunk-local scan with zero
// initial state (L) and the chunk decay product (P).
// L layout: [c][h][n][d], P layout: [c][h]
// CL is compile-time so the scan fully unrolls and loads pipeline deep.
// ---------------------------------------------------------------------------
template<int CL>
__global__ __launch_bounds__(64)
void phase1(const float* __restrict__ x, const float* __restrict__ dt,
            const float* __restrict__ B, const float* __restrict__ mask,
            const float* __restrict__ log_decay,
            float* __restrict__ Lbuf, float* __restrict__ Pbuf) {
    const int c = blockIdx.x, h = blockIdx.y;
    const int d = threadIdx.x;
    const float rate = -__expf(log_decay[h]);

    float s[N];
#pragma unroll
    for (int n = 0; n < N; ++n) s[n] = 0.f;
    float P = 1.f;

    const int t0 = c * CL;
#pragma unroll
    for (int ss = 0; ss < CL; ++ss) {
        const int t = t0 + ss;
        const float dtv  = dt[t * H + h];          // wave-uniform -> s_load
        const float mv   = mask[t];                // wave-uniform
        const float Atil = (1.f - mv) * __expf(dtv * rate);
        const float xv   = x[(t * H + h) * D + d]; // per-lane, coalesced
        const float cxd  = dtv * xv;
        const float* Bp  = B + (t * H + h) * N;    // wave-uniform -> s_load
        P *= Atil;
#pragma unroll
        for (int n = 0; n < N; ++n) {
            s[n] = Atil * s[n] + Bp[n] * cxd;
        }
    }

    float* Lp = Lbuf + ((c * H + h) * N) * D + d;
#pragma unroll
    for (int n = 0; n < N; ++n) Lp[n * D] = s[n];
    if (d == 0) Pbuf[c * H + h] = P;
}

// ---------------------------------------------------------------------------
// Phase 2: 16384 threads, one per (h,n,d). Sequentially combine chunks:
//   entry_c = carry;  carry = P_c * carry + L_c
// Overwrites L in place with the chunk ENTRY states. Writes next_carry.
// 16-deep load prefetch to hide latency on the serial chain.
// ---------------------------------------------------------------------------
__global__ __launch_bounds__(256)
void phase2(const float* __restrict__ initial_carry,
            float* __restrict__ LE, const float* __restrict__ Pbuf,
            float* __restrict__ next_carry, int NC) {
    const int idx = blockIdx.x * 256 + threadIdx.x;   // h*N*D + n*D + d
    const int h = idx >> 10;                          // N*D = 1024
    float carry = initial_carry[idx];

    for (int cg = 0; cg < NC; cg += 16) {
        float l[16], p[16];
#pragma unroll
        for (int k = 0; k < 16; ++k) {
            l[k] = LE[(cg + k) * (H * N * D) + idx];
            p[k] = Pbuf[(cg + k) * H + h];
        }
#pragma unroll
        for (int k = 0; k < 16; ++k) {
            LE[(cg + k) * (H * N * D) + idx] = carry; // entry state for chunk
            carry = p[k] * carry + l[k];
        }
    }
    next_carry[idx] = carry;
}

// ---------------------------------------------------------------------------
// Phase 3: re-scan each chunk from its entry state; fuse the C-projection
// (thread-local over n) and the skip connection. One coalesced store/step.
// ---------------------------------------------------------------------------
template<int CL>
__global__ __launch_bounds__(64)
void phase3(const float* __restrict__ x, const float* __restrict__ dt,
            const float* __restrict__ B, const float* __restrict__ C,
            const float* __restrict__ mask, const float* __restrict__ log_decay,
            const float* __restrict__ skip_weight,
            const float* __restrict__ Ebuf, float* __restrict__ out) {
    const int c = blockIdx.x, h = blockIdx.y;
    const int d = threadIdx.x;
    const float rate = -__expf(log_decay[h]);

    float s[N];
    const float* Ep = Ebuf + ((c * H + h) * N) * D + d;
#pragma unroll
    for (int n = 0; n < N; ++n) s[n] = Ep[n * D];

    const float sw = skip_weight[h * D + d];
    const int t0 = c * CL;
#pragma unroll
    for (int ss = 0; ss < CL; ++ss) {
        const int t = t0 + ss;
        const float dtv  = dt[t * H + h];
        const float mv   = mask[t];
        const float Atil = (1.f - mv) * __expf(dtv * rate);
        const float xv   = x[(t * H + h) * D + d];
        const float cxd  = dtv * xv;
        const float* Bp  = B + (t * H + h) * N;
        const float* Cp  = C + (t * H + h) * N;
        float acc = sw * xv;
#pragma unroll
        for (int n = 0; n < N; ++n) {
            s[n] = Atil * s[n] + Bp[n] * cxd;
            acc += Cp[n] * s[n];
        }
        out[(t * H + h) * D + d] = acc;
    }
}

template<int CL>
static void launch_all(const float* x, const float* dt, const float* B,
                       const float* C, const float* mask, const float* ic,
                       const float* ld, const float* sw, float* out,
                       float* Lbuf, float* Pbuf, hipStream_t stream) {
    constexpr int NC = T_LEN / CL;
    dim3 grid(NC, H), block(64);
    phase1<CL><<<grid, block, 0, stream>>>(x, dt, B, mask, ld, Lbuf, Pbuf);
    phase2<<<dim3(H * N * D / 256), dim3(256), 0, stream>>>(ic, Lbuf, Pbuf, out, NC);
    phase3<CL><<<grid, block, 0, stream>>>(x, dt, B, C, mask, ld, sw, Lbuf, out + H * N * D);
}

extern "C" void kernel_launch(void* const* d_in, const int* in_sizes, int n_in,
                              void* d_out, int out_size, void* d_ws, size_t ws_size,
                              hipStream_t stream) {
    const float* x    = (const float*)d_in[0];
    const float* dt   = (const float*)d_in[1];
    const float* B    = (const float*)d_in[2];
    const float* C    = (const float*)d_in[3];
    const float* mask = (const float*)d_in[4];
    const float* ic   = (const float*)d_in[5];
    const float* ld   = (const float*)d_in[6];
    const float* sw   = (const float*)d_in[7];
    float* out = (float*)d_out;

    float* Lbuf = (float*)d_ws;

    // Need NC*(H*N*D + H)*4 bytes of scratch.
    const size_t need256 = (size_t)256 * (H * N * D + H) * sizeof(float);
    const size_t need128 = need256 / 2;

    if (ws_size >= need256) {
        float* Pbuf = Lbuf + (size_t)256 * H * N * D;
        launch_all<T_LEN / 256>(x, dt, B, C, mask, ic, ld, sw, out, Lbuf, Pbuf, stream);
    } else if (ws_size >= need128) {
        float* Pbuf = Lbuf + (size_t)128 * H * N * D;
        launch_all<T_LEN / 128>(x, dt, B, C, mask, ic, ld, sw, out, Lbuf, Pbuf, stream);
    } else {
        float* Pbuf = Lbuf + (size_t)64 * H * N * D;
        launch_all<T_LEN / 64>(x, dt, B, C, mask, ic, ld, sw, out, Lbuf, Pbuf, stream);
    }
}

// Round 3
// 40.688 us; speedup vs baseline: 1.2688x; 1.2688x over previous
//
#include <hip/hip_runtime.h>

#define T_LEN 4096
#define H 16
#define N 16
#define D 64
#define NC 128
#define CL (T_LEN / NC)   // 32

// ---------------------------------------------------------------------------
// Phase 1: one wave per (chunk c, head h). Lane d owns the full n-column of
// the state (16 regs). B-panel for the chunk staged in LDS via 2 coalesced
// float4 loads/lane, then broadcast-read in the scan. Writes chunk-local
// result L[c][h][n][d] and decay product P[h][c].
// ---------------------------------------------------------------------------
__global__ __launch_bounds__(64)
void phase1(const float* __restrict__ x, const float* __restrict__ dt,
            const float* __restrict__ B, const float* __restrict__ mask,
            const float* __restrict__ log_decay,
            float* __restrict__ Lbuf, float* __restrict__ Pbuf) {
    const int c = blockIdx.x, h = blockIdx.y;
    const int d = threadIdx.x;
    const float rate = -__expf(log_decay[h]);
    const int t0 = c * CL;

    __shared__ float Bs[CL * N];                 // 2 KB
    {
        const float4* Bg = (const float4*)B;     // B rows are 64B-aligned
        float4* Bsv = (float4*)Bs;
#pragma unroll
        for (int i = 0; i < (CL * N / 4) / 64; ++i) {   // 2 iters
            const int j = i * 64 + d;
            const int row = j >> 2, off = j & 3;
            Bsv[j] = Bg[((t0 + row) * H + h) * (N / 4) + off];
        }
    }
    __syncthreads();

    float s[N];
#pragma unroll
    for (int n = 0; n < N; ++n) s[n] = 0.f;
    float P = 1.f;

#pragma unroll
    for (int ss = 0; ss < CL; ++ss) {
        const int t = t0 + ss;
        const float dtv = dt[t * H + h];          // wave-uniform
        const float mv  = mask[t];                // wave-uniform
        const float a   = (1.f - mv) * __expf(dtv * rate);
        const float xv  = x[(t * H + h) * D + d]; // per-lane coalesced
        const float cxd = dtv * xv;
        P *= a;
        const float* Br = Bs + ss * N;            // LDS broadcast reads
#pragma unroll
        for (int n = 0; n < N; ++n) s[n] = a * s[n] + Br[n] * cxd;
    }

    float* Lp = Lbuf + ((c * H + h) * N) * D + d;
#pragma unroll
    for (int n = 0; n < N; ++n) Lp[n * D] = s[n];
    if (d == 0) Pbuf[h * NC + c] = P;             // [h][c] for phase2 s_loads
}

// ---------------------------------------------------------------------------
// Phase 2: 16384 threads, one per (h,n,d). 64-deep prefetch (4.2 MB in
// flight across the grid -> BW-bound, not latency-bound). h is
// block-uniform so P loads scalarize. Overwrites L in place with chunk
// ENTRY states; writes next_carry.
// ---------------------------------------------------------------------------
__global__ __launch_bounds__(256)
void phase2(const float* __restrict__ initial_carry,
            float* __restrict__ LE, const float* __restrict__ Pbuf,
            float* __restrict__ next_carry) {
    const int idx = blockIdx.x * 256 + threadIdx.x;  // h*1024 + n*64 + d
    const int h = blockIdx.x >> 2;                   // block-uniform
    float carry = initial_carry[idx];

#pragma unroll
    for (int r = 0; r < NC / 64; ++r) {              // 2 rounds
        float l[64];
#pragma unroll
        for (int k = 0; k < 64; ++k)
            l[k] = LE[(r * 64 + k) * (H * N * D) + idx];
#pragma unroll
        for (int k = 0; k < 64; ++k) {
            const float p = Pbuf[h * NC + r * 64 + k];  // uniform -> s_load
            LE[(r * 64 + k) * (H * N * D) + idx] = carry;
            carry = p * carry + l[k];
        }
    }
    next_carry[idx] = carry;
}

// ---------------------------------------------------------------------------
// Phase 3: re-scan each chunk from its entry state, fusing the C-projection
// (thread-local over n) and the skip connection. B and C panels in LDS.
// ---------------------------------------------------------------------------
__global__ __launch_bounds__(64)
void phase3(const float* __restrict__ x, const float* __restrict__ dt,
            const float* __restrict__ B, const float* __restrict__ C,
            const float* __restrict__ mask, const float* __restrict__ log_decay,
            const float* __restrict__ skip_weight,
            const float* __restrict__ Ebuf, float* __restrict__ out) {
    const int c = blockIdx.x, h = blockIdx.y;
    const int d = threadIdx.x;
    const float rate = -__expf(log_decay[h]);
    const int t0 = c * CL;

    __shared__ float Bs[CL * N], Cs[CL * N];         // 4 KB
    {
        const float4* Bg = (const float4*)B;
        const float4* Cg = (const float4*)C;
        float4* Bsv = (float4*)Bs;
        float4* Csv = (float4*)Cs;
#pragma unroll
        for (int i = 0; i < (CL * N / 4) / 64; ++i) {
            const int j = i * 64 + d;
            const int row = j >> 2, off = j & 3;
            Bsv[j] = Bg[((t0 + row) * H + h) * (N / 4) + off];
            Csv[j] = Cg[((t0 + row) * H + h) * (N / 4) + off];
        }
    }
    __syncthreads();

    float s[N];
    const float* Ep = Ebuf + ((c * H + h) * N) * D + d;
#pragma unroll
    for (int n = 0; n < N; ++n) s[n] = Ep[n * D];

    const float sw = skip_weight[h * D + d];
#pragma unroll
    for (int ss = 0; ss < CL; ++ss) {
        const int t = t0 + ss;
        const float dtv = dt[t * H + h];
        const float mv  = mask[t];
        const float a   = (1.f - mv) * __expf(dtv * rate);
        const float xv  = x[(t * H + h) * D + d];
        const float cxd = dtv * xv;
        const float* Br = Bs + ss * N;
        const float* Cr = Cs + ss * N;
        float acc = sw * xv;
#pragma unroll
        for (int n = 0; n < N; ++n) {
            s[n] = a * s[n] + Br[n] * cxd;
            acc += Cr[n] * s[n];
        }
        out[(t * H + h) * D + d] = acc;
    }
}

extern "C" void kernel_launch(void* const* d_in, const int* in_sizes, int n_in,
                              void* d_out, int out_size, void* d_ws, size_t ws_size,
                              hipStream_t stream) {
    const float* x    = (const float*)d_in[0];
    const float* dt   = (const float*)d_in[1];
    const float* B    = (const float*)d_in[2];
    const float* C    = (const float*)d_in[3];
    const float* mask = (const float*)d_in[4];
    const float* ic   = (const float*)d_in[5];
    const float* ld   = (const float*)d_in[6];
    const float* sw   = (const float*)d_in[7];
    float* out = (float*)d_out;

    float* Lbuf = (float*)d_ws;                       // NC*H*N*D floats (8.4 MB)
    float* Pbuf = Lbuf + (size_t)NC * H * N * D;      // H*NC floats

    dim3 grid(NC, H), block(64);
    phase1<<<grid, block, 0, stream>>>(x, dt, B, mask, ld, Lbuf, Pbuf);
    phase2<<<dim3(H * N * D / 256), dim3(256), 0, stream>>>(ic, Lbuf, Pbuf, out);
    phase3<<<grid, block, 0, stream>>>(x, dt, B, C, mask, ld, sw, Lbuf, out + H * N * D);
}